// Round 1
// baseline (3489.368 us; speedup 1.0000x reference)
//
#include <hip/hip_runtime.h>

typedef _Float16 h2f __attribute__((ext_vector_type(2)));
typedef unsigned int u32;
typedef unsigned short u16;

#define B_ 128
#define S_ 1024
#define I_ 256
#define H_ 512
#define O_ 256
#define IH_ 768

// f16 pair dot with fp32 accumulate. v_dot2_f32_f16 if available (gfx9+), else
// unpack+fma fallback (correct, ~3x more VALU).
#if __has_builtin(__builtin_amdgcn_fdot2)
__device__ __forceinline__ float fdot2u(u32 a, u32 b, float c) {
    return __builtin_amdgcn_fdot2(__builtin_bit_cast(h2f, a),
                                  __builtin_bit_cast(h2f, b), c, false);
}
#else
__device__ __forceinline__ float fdot2u(u32 a, u32 b, float c) {
    h2f av = __builtin_bit_cast(h2f, a), bv = __builtin_bit_cast(h2f, b);
    return c + (float)av.x * (float)bv.x + (float)av.y * (float)bv.y;
}
#endif

__device__ __forceinline__ u32 pack2(float x, float y) {
    return __builtin_bit_cast(u32, __builtin_amdgcn_cvt_pkrtz(x, y));
}

__device__ __forceinline__ float tanh_fast(float x) {
    float e = __expf(-2.f * fabsf(x));     // e in (0,1] -- no overflow path
    float r = (1.f - e) / (1.f + e);
    return copysignf(r, x);
}

// ---------------------------------------------------------------------------
// Kernel A: repack W_i2h (512 x 768 fp32, row-major) into f16 pair-dwords.
//   wh[j*256 + m] = (W[j][256+2m], W[j][256+2m+1])   (Wh part, per-column)
//   wx[m*512 + j] = (W[j][2m],     W[j][2m+1])       (Wx part, [pair][col])
// ---------------------------------------------------------------------------
__global__ __launch_bounds__(256) void k_convert(const float* __restrict__ W,
                                                 u32* __restrict__ wh,
                                                 u32* __restrict__ wx) {
    int tid = blockIdx.x * 256 + threadIdx.x;
    if (tid < 512 * 256) {
        int j = tid >> 8, m = tid & 255;
        const float* r = W + j * IH_ + I_ + 2 * m;
        wh[j * 256 + m] = pack2(r[0], r[1]);
    } else {
        int k = tid - 512 * 256;           // < 128*512
        int m = k >> 9, j = k & 511;
        const float* r = W + j * IH_ + 2 * m;
        wx[m * 512 + j] = pack2(r[0], r[1]);
    }
}

// ---------------------------------------------------------------------------
// Phase 1: pre[r][j] = b_i2h[j] + sum_i x[r][i]*Wx[i][j], stored f16.
// r = b*1024+t flat (131072 rows). Grid 2048 = 1024 row-blocks x 2 col-halves,
// 256 threads = 256 columns. Wx column resident in VGPRs (128 pair-dwords);
// x row broadcast via one float4 load + cvt_pkrtz + v_readlane.
// ---------------------------------------------------------------------------
__global__ __launch_bounds__(256, 2) void k_phase1(const float* __restrict__ seq,
                                                   const u32* __restrict__ wx,
                                                   const float* __restrict__ bias,
                                                   u16* __restrict__ pre) {
    int half = blockIdx.x & 1;
    int rb   = blockIdx.x >> 1;
    int j    = half * 256 + threadIdx.x;
    int lane = threadIdx.x & 63;
    u32 w1[128];
#pragma unroll
    for (int m = 0; m < 128; ++m) w1[m] = wx[m * 512 + j];
    float bj = bias[j];
    int r0 = rb * 128;
    for (int rr = 0; rr < 128; ++rr) {
        int r = r0 + rr;
        const float4* xr = (const float4*)(seq + (long)r * I_);
        float4 xv = xr[lane];                    // lane l holds x[4l..4l+3]
        int s0 = (int)pack2(xv.x, xv.y);         // x-pair 2*l
        int s1 = (int)pack2(xv.z, xv.w);         // x-pair 2*l+1
        float a0 = bj, a1 = 0.f;
#pragma unroll
        for (int c = 0; c < 64; ++c) {
            a0 = fdot2u((u32)__builtin_amdgcn_readlane(s0, c), w1[2 * c + 0], a0);
            a1 = fdot2u((u32)__builtin_amdgcn_readlane(s1, c), w1[2 * c + 1], a1);
        }
        float acc = a0 + a1;
        pre[(long)r * H_ + j] = __builtin_bit_cast(u16, (_Float16)acc);
    }
}

// ---------------------------------------------------------------------------
// Phase 2: persistent recurrence. One WG per batch row (128 WGs x 512 thr).
// Thread j owns hidden column j. Wh column: pair-dwords 0..191 in VGPRs,
// 192..255 streamed from L2 each step. h ping-pong in LDS as f16; one
// ds_read_b128/wave/step gathers all 256 h pair-dwords, v_readlane broadcasts.
// One __syncthreads per step (ping-pong makes it sufficient).
// ---------------------------------------------------------------------------
__global__ __launch_bounds__(512, 2) void k_phase2(const u16* __restrict__ pre,
                                                   const u32* __restrict__ wh,
                                                   const float* __restrict__ Who,
                                                   const float* __restrict__ bo,
                                                   float* __restrict__ out) {
    __shared__ __align__(16) u16 hbuf[2][H_];
    int b = blockIdx.x;
    int j = threadIdx.x;
    int lane = j & 63;
    u32 w[192];
    const u32* gw = wh + j * 256;
#pragma unroll
    for (int m = 0; m < 192; ++m) w[m] = gw[m];
    const uint4* wst = (const uint4*)(gw + 192);   // 16 x uint4 streamed
    const u16* prow = pre + (long)b * S_ * H_;
    hbuf[0][j] = 0;                                // h0 = 0 (f16 +0.0)
    __syncthreads();
    u16 pv = prow[j];                              // pre for t=0
    for (int t = 0; t < S_; ++t) {
        int cur = t & 1, nxt = cur ^ 1;
        int tn = (t + 1 < S_) ? (t + 1) : t;
        u16 pnext = prow[(long)tn * H_ + j];       // prefetch next step's pre
        uint4 hv = ((const uint4*)hbuf[cur])[lane]; // lane l: h pair-dwords 4l..4l+3
        float a0 = (float)__builtin_bit_cast(_Float16, pv);
        float a1 = 0.f, a2 = 0.f, a3 = 0.f;
#pragma unroll
        for (int c = 0; c < 48; ++c) {             // register-resident weights
            a0 = fdot2u((u32)__builtin_amdgcn_readlane((int)hv.x, c), w[4 * c + 0], a0);
            a1 = fdot2u((u32)__builtin_amdgcn_readlane((int)hv.y, c), w[4 * c + 1], a1);
            a2 = fdot2u((u32)__builtin_amdgcn_readlane((int)hv.z, c), w[4 * c + 2], a2);
            a3 = fdot2u((u32)__builtin_amdgcn_readlane((int)hv.w, c), w[4 * c + 3], a3);
        }
#pragma unroll
        for (int c = 48; c < 64; ++c) {            // L2-streamed weights
            uint4 sw = wst[c - 48];
            a0 = fdot2u((u32)__builtin_amdgcn_readlane((int)hv.x, c), sw.x, a0);
            a1 = fdot2u((u32)__builtin_amdgcn_readlane((int)hv.y, c), sw.y, a1);
            a2 = fdot2u((u32)__builtin_amdgcn_readlane((int)hv.z, c), sw.z, a2);
            a3 = fdot2u((u32)__builtin_amdgcn_readlane((int)hv.w, c), sw.w, a3);
        }
        float acc = (a0 + a1) + (a2 + a3);
        float r = tanh_fast(acc);
        hbuf[nxt][j] = __builtin_bit_cast(u16, (_Float16)r);
        pv = pnext;
        __syncthreads();
    }
    // final h lives in hbuf[0] (last write: t=1023 -> nxt=0)
    float hj = (float)__builtin_bit_cast(_Float16, hbuf[0][j]);
    out[(long)B_ * O_ + (long)b * H_ + j] = hj;    // hidden output
    if (j < O_) {                                  // o = h @ W_h2o^T + b_h2o
        float acc = bo[j];
        const float4* wr = (const float4*)(Who + (long)j * H_);
        const u16* hb = hbuf[0];
#pragma unroll 4
        for (int k = 0; k < 128; ++k) {
            float4 wv = wr[k];
            acc += (float)__builtin_bit_cast(_Float16, hb[4 * k + 0]) * wv.x
                 + (float)__builtin_bit_cast(_Float16, hb[4 * k + 1]) * wv.y
                 + (float)__builtin_bit_cast(_Float16, hb[4 * k + 2]) * wv.z
                 + (float)__builtin_bit_cast(_Float16, hb[4 * k + 3]) * wv.w;
        }
        out[(long)b * O_ + j] = acc;
    }
}

// ---------------------------------------------------------------------------
// Fallback (workspace too small): straightforward fp32, correct but slow.
// ---------------------------------------------------------------------------
__global__ __launch_bounds__(512) void k_fallback(const float* __restrict__ seq,
                                                  const float* __restrict__ W,
                                                  const float* __restrict__ bias,
                                                  const float* __restrict__ Who,
                                                  const float* __restrict__ bo,
                                                  float* __restrict__ out) {
    __shared__ float hb[2][H_];
    int b = blockIdx.x, j = threadIdx.x;
    const float* wrow = W + (long)j * IH_;
    float bj = bias[j];
    hb[0][j] = 0.f;
    __syncthreads();
    for (int t = 0; t < S_; ++t) {
        const float* x = seq + ((long)b * S_ + t) * I_;
        float acc = bj;
        for (int i = 0; i < I_; ++i) acc += x[i] * wrow[i];
        const float* hc = hb[t & 1];
        for (int k = 0; k < H_; ++k) acc += hc[k] * wrow[I_ + k];
        hb[(t & 1) ^ 1][j] = tanh_fast(acc);
        __syncthreads();
    }
    float hj = hb[0][j];
    out[(long)B_ * O_ + (long)b * H_ + j] = hj;
    if (j < O_) {
        float acc = bo[j];
        const float* wr = Who + (long)j * H_;
        for (int k = 0; k < H_; ++k) acc += hb[0][k] * wr[k];
        out[(long)b * O_ + j] = acc;
    }
}

extern "C" void kernel_launch(void* const* d_in, const int* in_sizes, int n_in,
                              void* d_out, int out_size, void* d_ws, size_t ws_size,
                              hipStream_t stream) {
    const float* seq = (const float*)d_in[0];   // (128,1024,256) fp32
    const float* W   = (const float*)d_in[1];   // (512,768) fp32
    const float* bi  = (const float*)d_in[2];   // (512,)
    const float* Who = (const float*)d_in[3];   // (256,512)
    const float* bo  = (const float*)d_in[4];   // (256,)
    float* out = (float*)d_out;                 // 32768 output + 65536 hidden

    const size_t PRE_OFF = 1u << 20;                              // 1 MB for packed weights
    const size_t WS_NEED = PRE_OFF + (size_t)B_ * S_ * H_ * 2;    // + 128 MB f16 pre

    if (ws_size >= WS_NEED) {
        u32* wh  = (u32*)d_ws;                  // 512*256 dwords = 512 KB
        u32* wx  = wh + 512 * 256;              // 128*512 dwords = 256 KB
        u16* pre = (u16*)((char*)d_ws + PRE_OFF);
        k_convert<<<768, 256, 0, stream>>>(W, wh, wx);
        k_phase1<<<2048, 256, 0, stream>>>(seq, wx, bi, pre);
        k_phase2<<<B_, 512, 0, stream>>>(pre, wh, Who, bo, out);
    } else {
        k_fallback<<<B_, 512, 0, stream>>>(seq, W, bi, Who, bo, out);
    }
}